// Round 8
// baseline (186.900 us; speedup 1.0000x reference)
//
#include <hip/hip_runtime.h>
#include <hip/hip_bf16.h>
#include <math.h>

#define LVL 10
#define TBL 65536u
#define HIDN 64
#define OUTD 29
#define DIN 40

typedef __attribute__((ext_vector_type(8))) short short8;
typedef __attribute__((ext_vector_type(4))) float f32x4;

struct ResArr { float r[LVL]; };

__device__ __forceinline__ unsigned short f2bf(float v) {
    __hip_bfloat16 b = __float2bfloat16(v);
    return __builtin_bit_cast(unsigned short, b);
}
__device__ __forceinline__ float selu_f(float v) {
    return v > 0.f ? 1.0507009873554805f * v
                   : 1.7580993408473766f * (__expf(v) - 1.f);
}

// ---------- kernel 0a: fp32 table -> bf16 table (d_ws) ----------
__global__ __launch_bounds__(256) void cvt_table(const float4* __restrict__ tbl,
                                                 uint2* __restrict__ tblbf) {
    const int i = blockIdx.x * 256 + threadIdx.x;
    if (i >= (int)(TBL * LVL)) return;
    const float4 f = tbl[i];
    uint2 q;
    q.x = (unsigned)f2bf(f.x) | ((unsigned)f2bf(f.y) << 16);
    q.y = (unsigned)f2bf(f.z) | ((unsigned)f2bf(f.w) << 16);
    tblbf[i] = q;
}

// ---------- kernel 0b: weight/bias fragments (30720 B) ----------
__global__ __launch_bounds__(256) void build_frags(
    const float* __restrict__ W1, const float* __restrict__ b1,
    const float* __restrict__ W2, const float* __restrict__ b2,
    const float* __restrict__ W3, const float* __restrict__ b3,
    unsigned short* __restrict__ frag) {
    const int i = blockIdx.x * 256 + threadIdx.x;
    const int lane = i & 63, c = lane & 15, g = lane >> 4;
    if (i < 1280) {
        const int slot = i >> 6;
        float v[8];
#pragma unroll
        for (int j = 0; j < 8; ++j) v[j] = 0.f;
        if (slot < 8) {
            const int mt = slot >> 1, half = slot & 1, row = mt * 16 + c;
            if (half == 0) { for (int j = 0; j < 8; ++j) v[j] = W1[row*DIN + g*8 + j]; }
            else if (g == 0) { for (int j = 0; j < 8; ++j) v[j] = W1[row*DIN + 32 + j]; }
        } else if (slot < 16) {
            const int s = slot - 8, mt = s >> 1, ks = s & 1, row = mt * 16 + c;
            for (int j = 0; j < 8; ++j) v[j] = W2[row*HIDN + ks*32 + g*8 + j];
        } else {
            const int s = slot - 16, rt = s >> 1, ks = s & 1, row = rt * 16 + c;
            if (row < OUTD) { for (int j = 0; j < 8; ++j) v[j] = W3[row*HIDN + ks*32 + g*8 + j]; }
        }
        short8 r;
#pragma unroll
        for (int j = 0; j < 8; ++j) r[j] = (short)f2bf(v[j]);
        ((short8*)frag)[i] = r;
    } else if (i < 1920) {
        const int s = (i - 1280) >> 6;   // 0..9
        f32x4 v = {0.f, 0.f, 0.f, 0.f};
#pragma unroll
        for (int r = 0; r < 4; ++r) {
            if (s < 4)      v[r] = b1[s*16 + g*4 + r];
            else if (s < 8) v[r] = b2[(s-4)*16 + g*4 + r];
            else { const int row = (s-8)*16 + g*4 + r; v[r] = (row < OUTD) ? b3[row] : 0.f; }
        }
        ((f32x4*)(frag + 10240))[i - 1280] = v;
    }
}

// ---------- kernel 1: gather; thread = (point, k, level-half) ----------
// Phase A issues ALL 40 loads (5 levels x 8 corners) before phase B consumes
// them level-by-level -> counted vmcnt instead of drain-to-0 per level.
template<bool BF>
__global__ __launch_bounds__(256, 4) void ingp_gather(
    const float* __restrict__ xg, const float* __restrict__ crg,
    const float* __restrict__ epsg, const float* __restrict__ table,
    const uint2* __restrict__ tblbf,
    unsigned short* __restrict__ hswz, int npts, ResArr res)
{
    const int t   = threadIdx.x;
    const int k   = t & 3;
    const int lh  = (t >> 2) & 1;
    const int pib = t >> 3;
    const int pg  = blockIdx.x * 32 + pib;

    {   // zero K-pad (shorts [640,1024)) of this block's 2 tiles
        const int tile0 = blockIdx.x * 2;
        for (int i = t; i < 384; i += 256) {
            const int tl = i / 192, off = i - tl * 192;
            const int tile = tile0 + tl;
            if (tile * 16 < npts)
                ((unsigned*)(hswz + (size_t)tile * 1024 + 640))[off] = 0u;
        }
    }
    if (pg >= npts) return;

    const int tile = pg >> 4, c = pg & 15;
    unsigned short* tb = hswz + (size_t)tile * 1024;

    const float crv = crg[pg];
    const float tc  = 0.3f * crv;
    const float cvx = fmaf(4.f, xg[pg*3+0], -2.f);
    const float cvy = fmaf(4.f, xg[pg*3+1], -2.f);
    const float cvz = fmaf(4.f, xg[pg*3+2], -2.f);
    const float* ep = epsg + ((size_t)pg * 4 + k) * 3;
    const float sx = fmaf(fminf(fmaxf(fmaf(ep[0], tc, cvx), -1.f), 1.f), 0.25f, 0.5f);
    const float sy = fmaf(fminf(fmaxf(fmaf(ep[1], tc, cvy), -1.f), 1.f), 0.25f, 0.5f);
    const float sz = fmaf(fminf(fmaxf(fmaf(ep[2], tc, cvz), -1.f), 1.f), 0.25f, 0.5f);

    if (BF) {
        uint2 qq[5][8];                 // 80 VGPRs of in-flight data
        float frx[5], fry[5], frz[5];
        // ---- phase A: compute hashes, issue all 40 loads ----
#pragma unroll
        for (int li = 0; li < 5; ++li) {
            const int l = lh * 5 + li;
            const float rs = lh ? res.r[li + 5] : res.r[li];
            const float xs = sx * rs, ys = sy * rs, zs = sz * rs;
            const float fx = floorf(xs), fy = floorf(ys), fz = floorf(zs);
            frx[li] = xs - fx; fry[li] = ys - fy; frz[li] = zs - fz;
            const unsigned cx = (unsigned)fx, cy = (unsigned)fy, cz = (unsigned)fz;
            const unsigned hx0 = cx,               hx1 = cx + 1u;
            const unsigned hy0 = cy * 2654435761u, hy1 = hy0 + 2654435761u;
            const unsigned hz0 = cz * 805459861u,  hz1 = hz0 + 805459861u;
            const uint2* tp = tblbf + (size_t)l * TBL;
            qq[li][0] = tp[(hx0^hy0^hz0) & (TBL-1u)];
            qq[li][1] = tp[(hx0^hy0^hz1) & (TBL-1u)];
            qq[li][2] = tp[(hx0^hy1^hz0) & (TBL-1u)];
            qq[li][3] = tp[(hx0^hy1^hz1) & (TBL-1u)];
            qq[li][4] = tp[(hx1^hy0^hz0) & (TBL-1u)];
            qq[li][5] = tp[(hx1^hy0^hz1) & (TBL-1u)];
            qq[li][6] = tp[(hx1^hy1^hz0) & (TBL-1u)];
            qq[li][7] = tp[(hx1^hy1^hz1) & (TBL-1u)];
        }
        // ---- phase B: consume level-by-level ----
#pragma unroll
        for (int li = 0; li < 5; ++li) {
            const int l = lh * 5 + li;
            const float wx1 = frx[li], wx0 = 1.f - wx1;
            const float wy1 = fry[li], wy0 = 1.f - wy1;
            const float wz1 = frz[li], wz0 = 1.f - wz1;
            const float w0 = wx0*wy0*wz0, w1 = wx0*wy0*wz1, w2 = wx0*wy1*wz0, w3 = wx0*wy1*wz1;
            const float w4 = wx1*wy0*wz0, w5 = wx1*wy0*wz1, w6 = wx1*wy1*wz0, w7 = wx1*wy1*wz1;
            float ax = 0.f, ay = 0.f, az = 0.f, aw = 0.f;
#define CBF(Q,W) do { \
                ax = fmaf(W, __uint_as_float((Q).x << 16),        ax); \
                ay = fmaf(W, __uint_as_float((Q).x & 0xffff0000u), ay); \
                az = fmaf(W, __uint_as_float((Q).y << 16),        az); \
                aw = fmaf(W, __uint_as_float((Q).y & 0xffff0000u), aw); } while (0)
            CBF(qq[li][0],w0); CBF(qq[li][1],w1); CBF(qq[li][2],w2); CBF(qq[li][3],w3);
            CBF(qq[li][4],w4); CBF(qq[li][5],w5); CBF(qq[li][6],w6); CBF(qq[li][7],w7);
#undef CBF
            ax += __shfl_xor(ax, 1, 64); ay += __shfl_xor(ay, 1, 64);
            az += __shfl_xor(az, 1, 64); aw += __shfl_xor(aw, 1, 64);
            ax += __shfl_xor(ax, 2, 64); ay += __shfl_xor(ay, 2, 64);
            az += __shfl_xor(az, 2, 64); aw += __shfl_xor(aw, 2, 64);
            const float den = fmaxf(8.f * (float)l * crv, 1e-12f);
            const float s = 0.25f * erff(rsqrtf(den));
            const float v = (k & 1) ? ((k & 2) ? aw : ay) : ((k & 2) ? az : ax);
            const int f = k * LVL + l;
            const int a = ((f >> 5) << 9) + (((f >> 3) & 3) << 7) + (c << 3) + (f & 7);
            tb[a] = f2bf(v * s);
        }
    } else {
        // fp32 fallback (old per-level structure)
#pragma unroll
        for (int li = 0; li < 5; ++li) {
            const int l = lh * 5 + li;
            const float rs = lh ? res.r[li + 5] : res.r[li];
            const float xs = sx * rs, ys = sy * rs, zs = sz * rs;
            const float fx = floorf(xs), fy = floorf(ys), fz = floorf(zs);
            const float frx = xs - fx, fry = ys - fy, frz = zs - fz;
            const unsigned cx = (unsigned)fx, cy = (unsigned)fy, cz = (unsigned)fz;
            const unsigned hx0 = cx,               hx1 = cx + 1u;
            const unsigned hy0 = cy * 2654435761u, hy1 = hy0 + 2654435761u;
            const unsigned hz0 = cz * 805459861u,  hz1 = hz0 + 805459861u;
            const float4* tp = (const float4*)table + (size_t)l * TBL;
            const float4 f0 = tp[(hx0^hy0^hz0) & (TBL-1u)], f1 = tp[(hx0^hy0^hz1) & (TBL-1u)];
            const float4 f2 = tp[(hx0^hy1^hz0) & (TBL-1u)], f3 = tp[(hx0^hy1^hz1) & (TBL-1u)];
            const float4 f4 = tp[(hx1^hy0^hz0) & (TBL-1u)], f5 = tp[(hx1^hy0^hz1) & (TBL-1u)];
            const float4 f6 = tp[(hx1^hy1^hz0) & (TBL-1u)], f7 = tp[(hx1^hy1^hz1) & (TBL-1u)];
            const float wx1 = frx, wx0 = 1.f - frx;
            const float wy1 = fry, wy0 = 1.f - fry;
            const float wz1 = frz, wz0 = 1.f - frz;
            const float w0 = wx0*wy0*wz0, w1 = wx0*wy0*wz1, w2 = wx0*wy1*wz0, w3 = wx0*wy1*wz1;
            const float w4 = wx1*wy0*wz0, w5 = wx1*wy0*wz1, w6 = wx1*wy1*wz0, w7 = wx1*wy1*wz1;
            float ax = w0*f0.x + w1*f1.x + w2*f2.x + w3*f3.x + w4*f4.x + w5*f5.x + w6*f6.x + w7*f7.x;
            float ay = w0*f0.y + w1*f1.y + w2*f2.y + w3*f3.y + w4*f4.y + w5*f5.y + w6*f6.y + w7*f7.y;
            float az = w0*f0.z + w1*f1.z + w2*f2.z + w3*f3.z + w4*f4.z + w5*f5.z + w6*f6.z + w7*f7.z;
            float aw = w0*f0.w + w1*f1.w + w2*f2.w + w3*f3.w + w4*f4.w + w5*f5.w + w6*f6.w + w7*f7.w;
            ax += __shfl_xor(ax, 1, 64); ay += __shfl_xor(ay, 1, 64);
            az += __shfl_xor(az, 1, 64); aw += __shfl_xor(aw, 1, 64);
            ax += __shfl_xor(ax, 2, 64); ay += __shfl_xor(ay, 2, 64);
            az += __shfl_xor(az, 2, 64); aw += __shfl_xor(aw, 2, 64);
            const float den = fmaxf(8.f * (float)l * crv, 1e-12f);
            const float s = 0.25f * erff(rsqrtf(den));
            const float v = (k & 1) ? ((k & 2) ? aw : ay) : ((k & 2) ? az : ax);
            const int f = k * LVL + l;
            const int a = ((f >> 5) << 9) + (((f >> 3) & 3) << 7) + (c << 3) + (f & 7);
            tb[a] = f2bf(v * s);
        }
    }
}

// ---------- kernel 2: MFMA MLP, wave = 16-point tile ----------
__global__ __launch_bounds__(256, 4) void ingp_mlp(
    const unsigned short* __restrict__ hswz,
    const unsigned short* __restrict__ frag,
    float* __restrict__ out, int npts)
{
    __shared__ __align__(16) char lds[4][2][2304];
    const int t    = threadIdx.x;
    const int lane = t & 63;
    const int wv   = t >> 6;
    const int c    = lane & 15;
    const int g    = lane >> 4;
    const int tile = blockIdx.x * 4 + wv;
    char* bufA = lds[wv][0];
    char* bufB = lds[wv][1];

    const short8* Fa = (const short8*)frag;
    const f32x4*  Fb = (const f32x4*)(frag + 10240);

    // ---- GEMM1: h1 = selu(W1 @ h + b1), K=64 (padded) ----
    const short8* Hf = (const short8*)(hswz + (size_t)tile * 1024);
    const short8 hb0 = Hf[lane];
    const short8 hb1 = Hf[64 + lane];
    f32x4 acc[4];
#pragma unroll
    for (int mt = 0; mt < 4; ++mt) {
        const short8 a0 = Fa[(mt*2    )*64 + lane];
        const short8 a1 = Fa[(mt*2 + 1)*64 + lane];
        f32x4 acr = {0.f, 0.f, 0.f, 0.f};
        acr = __builtin_amdgcn_mfma_f32_16x16x32_bf16(a0, hb0, acr, 0, 0, 0);
        acr = __builtin_amdgcn_mfma_f32_16x16x32_bf16(a1, hb1, acr, 0, 0, 0);
        acc[mt] = acr;
    }
#pragma unroll
    for (int mt = 0; mt < 4; ++mt) {
        const f32x4 bb = Fb[mt*64 + lane];
        unsigned short h4[4];
#pragma unroll
        for (int r = 0; r < 4; ++r) h4[r] = f2bf(selu_f(acc[mt][r] + bb[r]));
        uint2 pk;
        pk.x = (unsigned)h4[0] | ((unsigned)h4[1] << 16);
        pk.y = (unsigned)h4[2] | ((unsigned)h4[3] << 16);
        *(uint2*)(bufA + c * 144 + mt * 32 + g * 8) = pk;
    }
    __syncthreads();

    // ---- GEMM2: h2 = selu(W2 @ h1 + b2), K=64 -> 2 k-slices ----
    short8 h1f[2];
#pragma unroll
    for (int ks = 0; ks < 2; ++ks)
        h1f[ks] = *(const short8*)(bufA + c * 144 + ks * 64 + g * 16);
    f32x4 acc2[4];
#pragma unroll
    for (int mt = 0; mt < 4; ++mt) {
        f32x4 acr = {0.f, 0.f, 0.f, 0.f};
#pragma unroll
        for (int ks = 0; ks < 2; ++ks) {
            const short8 af = Fa[(8 + mt*2 + ks)*64 + lane];
            acr = __builtin_amdgcn_mfma_f32_16x16x32_bf16(af, h1f[ks], acr, 0, 0, 0);
        }
        acc2[mt] = acr;
    }
    __syncthreads();
#pragma unroll
    for (int mt = 0; mt < 4; ++mt) {
        const f32x4 bb = Fb[(4 + mt)*64 + lane];
        unsigned short h4[4];
#pragma unroll
        for (int r = 0; r < 4; ++r) h4[r] = f2bf(selu_f(acc2[mt][r] + bb[r]));
        uint2 pk;
        pk.x = (unsigned)h4[0] | ((unsigned)h4[1] << 16);
        pk.y = (unsigned)h4[2] | ((unsigned)h4[3] << 16);
        *(uint2*)(bufB + c * 144 + mt * 32 + g * 8) = pk;
    }
    __syncthreads();

    // ---- GEMM3: o = W3 @ h2 + b3 (29 rows padded to 32), K=64 -> 2 slices ----
    short8 h2f[2];
#pragma unroll
    for (int ks = 0; ks < 2; ++ks)
        h2f[ks] = *(const short8*)(bufB + c * 144 + ks * 64 + g * 16);
    f32x4 o0 = {0.f,0.f,0.f,0.f}, o1 = {0.f,0.f,0.f,0.f};
#pragma unroll
    for (int ks = 0; ks < 2; ++ks) {
        const short8 af0 = Fa[(16 + ks)*64 + lane];
        o0 = __builtin_amdgcn_mfma_f32_16x16x32_bf16(af0, h2f[ks], o0, 0, 0, 0);
        const short8 af1 = Fa[(18 + ks)*64 + lane];
        o1 = __builtin_amdgcn_mfma_f32_16x16x32_bf16(af1, h2f[ks], o1, 0, 0, 0);
    }
    __syncthreads();   // bufA free again
    {
        const f32x4 bb0 = Fb[8*64 + lane];
        const f32x4 bb1 = Fb[9*64 + lane];
        f32x4 v0, v1;
#pragma unroll
        for (int r = 0; r < 4; ++r) { v0[r] = o0[r] + bb0[r]; v1[r] = o1[r] + bb1[r]; }
        *(f32x4*)(bufA + c * 144 + g * 16)      = v0;
        *(f32x4*)(bufA + c * 144 + 64 + g * 16) = v1;
    }
    __syncthreads();

    // ---- epilogue: quad per point ----
    {
        const int c2 = lane >> 2, part = lane & 3;
        const float* op = (const float*)(bufA + c2 * 144);
        const size_t p = (size_t)tile * 16 + c2;
        if ((int)p < npts) {
            float* dns  = out;
            float* rgbp = out + (size_t)npts;
            float* grdp = out + (size_t)npts * 4;
            float* shp  = out + (size_t)npts * 13;
            if (part == 0) {
                dns[p] = expf(op[0] - 4.f);
                rgbp[p*3+0] = op[1] + 0.5f;
                rgbp[p*3+1] = op[2] + 0.5f;
                rgbp[p*3+2] = op[3] + 0.5f;
            } else {
                const int r = part - 1;
                const float rr = op[1 + r] + 0.5f;
                grdp[p*9 + r*3 + 0] = rr * tanhf(op[4 + r*3 + 0]);
                grdp[p*9 + r*3 + 1] = rr * tanhf(op[4 + r*3 + 1]);
                grdp[p*9 + r*3 + 2] = rr * tanhf(op[4 + r*3 + 2]);
            }
#pragma unroll
            for (int s = 0; s < 4; ++s)
                shp[p*16 + part*4 + s] = op[13 + part*4 + s];
        }
    }
}

extern "C" void kernel_launch(void* const* d_in, const int* in_sizes, int n_in,
                              void* d_out, int out_size, void* d_ws, size_t ws_size,
                              hipStream_t stream) {
    const float* x     = (const float*)d_in[0];
    const float* cr    = (const float*)d_in[1];
    const float* eps   = (const float*)d_in[2];
    const float* table = (const float*)d_in[3];
    const float* W1    = (const float*)d_in[4];
    const float* b1    = (const float*)d_in[5];
    const float* W2    = (const float*)d_in[6];
    const float* b2    = (const float*)d_in[7];
    const float* W3    = (const float*)d_in[8];
    const float* b3    = (const float*)d_in[9];
    float* out = (float*)d_out;

    const int npts   = in_sizes[0] / 3;
    const size_t ntiles = (size_t)(npts + 15) / 16;
    const size_t tblbf_bytes = (size_t)TBL * LVL * 8;     // 5,242,880
    const size_t frag_bytes  = 30720;
    const size_t hswz_bytes  = ntiles * 2048;
    const bool   bfpath = ws_size >= tblbf_bytes + frag_bytes + hswz_bytes;

    char* wsb = (char*)d_ws;
    uint2*          tblbf;
    unsigned short* frag;
    unsigned short* hswz;
    if (bfpath) {
        tblbf = (uint2*)wsb;
        frag  = (unsigned short*)(wsb + tblbf_bytes);
        hswz  = (unsigned short*)(wsb + tblbf_bytes + frag_bytes);
    } else {
        tblbf = (uint2*)table;   // unused in fp32 path
        frag  = (unsigned short*)wsb;
        hswz  = (unsigned short*)(wsb + frag_bytes);
    }

    ResArr res;
    const double bg = exp(log(pow(2.0, 10.0)) / 9.0);
    for (int l = 0; l < LVL; ++l) res.r[l] = (float)floor(16.0 * pow(bg, (double)l));

    if (bfpath)
        hipLaunchKernelGGL(cvt_table, dim3((TBL*LVL + 255)/256), dim3(256), 0, stream,
                           (const float4*)table, tblbf);
    hipLaunchKernelGGL(build_frags, dim3(8), dim3(256), 0, stream,
                       W1, b1, W2, b2, W3, b3, frag);

    const int grid1 = (npts + 31) / 32;
    if (bfpath)
        hipLaunchKernelGGL(ingp_gather<true>, dim3(grid1), dim3(256), 0, stream,
                           x, cr, eps, table, tblbf, hswz, npts, res);
    else
        hipLaunchKernelGGL(ingp_gather<false>, dim3(grid1), dim3(256), 0, stream,
                           x, cr, eps, table, tblbf, hswz, npts, res);

    const int grid2 = (npts + 63) / 64;
    hipLaunchKernelGGL(ingp_mlp, dim3(grid2), dim3(256), 0, stream,
                       hswz, frag, out, npts);
}

// Round 9
// 162.451 us; speedup vs baseline: 1.1505x; 1.1505x over previous
//
#include <hip/hip_runtime.h>
#include <hip/hip_bf16.h>
#include <math.h>

#define LVL 10
#define TBL 65536u
#define HIDN 64
#define OUTD 29
#define DIN 40

typedef __attribute__((ext_vector_type(8))) short short8;
typedef __attribute__((ext_vector_type(4))) float f32x4;

struct ResArr { float r[LVL]; };

__device__ __forceinline__ unsigned short f2bf(float v) {
    __hip_bfloat16 b = __float2bfloat16(v);
    return __builtin_bit_cast(unsigned short, b);
}
__device__ __forceinline__ float selu_f(float v) {
    return v > 0.f ? 1.0507009873554805f * v
                   : 1.7580993408473766f * (__expf(v) - 1.f);
}

// ---------- kernel 0a: fp32 table -> bf16 table (d_ws) ----------
__global__ __launch_bounds__(256) void cvt_table(const float4* __restrict__ tbl,
                                                 uint2* __restrict__ tblbf) {
    const int i = blockIdx.x * 256 + threadIdx.x;
    if (i >= (int)(TBL * LVL)) return;
    const float4 f = tbl[i];
    uint2 q;
    q.x = (unsigned)f2bf(f.x) | ((unsigned)f2bf(f.y) << 16);
    q.y = (unsigned)f2bf(f.z) | ((unsigned)f2bf(f.w) << 16);
    tblbf[i] = q;
}

// ---------- kernel 0b: weight/bias fragments (30720 B) ----------
__global__ __launch_bounds__(256) void build_frags(
    const float* __restrict__ W1, const float* __restrict__ b1,
    const float* __restrict__ W2, const float* __restrict__ b2,
    const float* __restrict__ W3, const float* __restrict__ b3,
    unsigned short* __restrict__ frag) {
    const int i = blockIdx.x * 256 + threadIdx.x;
    const int lane = i & 63, c = lane & 15, g = lane >> 4;
    if (i < 1280) {
        const int slot = i >> 6;
        float v[8];
#pragma unroll
        for (int j = 0; j < 8; ++j) v[j] = 0.f;
        if (slot < 8) {
            const int mt = slot >> 1, half = slot & 1, row = mt * 16 + c;
            if (half == 0) { for (int j = 0; j < 8; ++j) v[j] = W1[row*DIN + g*8 + j]; }
            else if (g == 0) { for (int j = 0; j < 8; ++j) v[j] = W1[row*DIN + 32 + j]; }
        } else if (slot < 16) {
            const int s = slot - 8, mt = s >> 1, ks = s & 1, row = mt * 16 + c;
            for (int j = 0; j < 8; ++j) v[j] = W2[row*HIDN + ks*32 + g*8 + j];
        } else {
            const int s = slot - 16, rt = s >> 1, ks = s & 1, row = rt * 16 + c;
            if (row < OUTD) { for (int j = 0; j < 8; ++j) v[j] = W3[row*HIDN + ks*32 + g*8 + j]; }
        }
        short8 r;
#pragma unroll
        for (int j = 0; j < 8; ++j) r[j] = (short)f2bf(v[j]);
        ((short8*)frag)[i] = r;
    } else if (i < 1920) {
        const int s = (i - 1280) >> 6;   // 0..9
        f32x4 v = {0.f, 0.f, 0.f, 0.f};
#pragma unroll
        for (int r = 0; r < 4; ++r) {
            if (s < 4)      v[r] = b1[s*16 + g*4 + r];
            else if (s < 8) v[r] = b2[(s-4)*16 + g*4 + r];
            else { const int row = (s-8)*16 + g*4 + r; v[r] = (row < OUTD) ? b3[row] : 0.f; }
        }
        ((f32x4*)(frag + 10240))[i - 1280] = v;
    }
}

// ---------- kernel 1: gather; thread = (point, k, LEVEL) ----------
// unit u = point*10 + level; lanes 4u..4u+3 hold k=0..3 -> shfl_xor(1,2) k-reduce.
// 8 loads in flight per thread (proven spill-free), 10x wave count of R7.
template<bool BF>
__global__ __launch_bounds__(256, 6) void ingp_gather(
    const float* __restrict__ xg, const float* __restrict__ crg,
    const float* __restrict__ epsg, const float* __restrict__ table,
    const uint2* __restrict__ tblbf,
    unsigned short* __restrict__ hswz, int nunits, int npts, ResArr res)
{
    const int t = threadIdx.x;
    const int k = t & 3;
    const int u = blockIdx.x * 64 + (t >> 2);
    if (u >= nunits) return;

    // u -> (point, level)  (compiler lowers /10 to magic-mul)
    const int pg = u / 10;
    const int l  = u - pg * 10;
    const int tile = pg >> 4, c = pg & 15;

    // static-index select of res.r[l] (no dynamic kernarg indexing -> no scratch)
    float rs = res.r[0];
    rs = (l == 1) ? res.r[1] : rs;  rs = (l == 2) ? res.r[2] : rs;
    rs = (l == 3) ? res.r[3] : rs;  rs = (l == 4) ? res.r[4] : rs;
    rs = (l == 5) ? res.r[5] : rs;  rs = (l == 6) ? res.r[6] : rs;
    rs = (l == 7) ? res.r[7] : rs;  rs = (l == 8) ? res.r[8] : rs;
    rs = (l == 9) ? res.r[9] : rs;

    const float crv = crg[pg];
    const float tc  = 0.3f * crv;
    const float cvx = fmaf(4.f, xg[pg*3+0], -2.f);
    const float cvy = fmaf(4.f, xg[pg*3+1], -2.f);
    const float cvz = fmaf(4.f, xg[pg*3+2], -2.f);
    const float* ep = epsg + ((size_t)pg * 4 + k) * 3;
    const float sx = fmaf(fminf(fmaxf(fmaf(ep[0], tc, cvx), -1.f), 1.f), 0.25f, 0.5f);
    const float sy = fmaf(fminf(fmaxf(fmaf(ep[1], tc, cvy), -1.f), 1.f), 0.25f, 0.5f);
    const float sz = fmaf(fminf(fmaxf(fmaf(ep[2], tc, cvz), -1.f), 1.f), 0.25f, 0.5f);

    const float xs = sx * rs, ys = sy * rs, zs = sz * rs;
    const float fx = floorf(xs), fy = floorf(ys), fz = floorf(zs);
    const float frx = xs - fx, fry = ys - fy, frz = zs - fz;
    const unsigned cx = (unsigned)fx, cy = (unsigned)fy, cz = (unsigned)fz;
    const unsigned hx0 = cx,               hx1 = cx + 1u;
    const unsigned hy0 = cy * 2654435761u, hy1 = hy0 + 2654435761u;
    const unsigned hz0 = cz * 805459861u,  hz1 = hz0 + 805459861u;
    const unsigned i0 = (hx0^hy0^hz0) & (TBL-1u);
    const unsigned i1 = (hx0^hy0^hz1) & (TBL-1u);
    const unsigned i2 = (hx0^hy1^hz0) & (TBL-1u);
    const unsigned i3 = (hx0^hy1^hz1) & (TBL-1u);
    const unsigned i4 = (hx1^hy0^hz0) & (TBL-1u);
    const unsigned i5 = (hx1^hy0^hz1) & (TBL-1u);
    const unsigned i6 = (hx1^hy1^hz0) & (TBL-1u);
    const unsigned i7 = (hx1^hy1^hz1) & (TBL-1u);
    const float wx1 = frx, wx0 = 1.f - frx;
    const float wy1 = fry, wy0 = 1.f - fry;
    const float wz1 = frz, wz0 = 1.f - frz;
    const float w0 = wx0*wy0*wz0, w1 = wx0*wy0*wz1, w2 = wx0*wy1*wz0, w3 = wx0*wy1*wz1;
    const float w4 = wx1*wy0*wz0, w5 = wx1*wy0*wz1, w6 = wx1*wy1*wz0, w7 = wx1*wy1*wz1;

    float ax = 0.f, ay = 0.f, az = 0.f, aw = 0.f;
    if (BF) {
        const uint2* tp = tblbf + (size_t)l * TBL;
        const uint2 q0 = tp[i0], q1 = tp[i1], q2 = tp[i2], q3 = tp[i3];
        const uint2 q4 = tp[i4], q5 = tp[i5], q6 = tp[i6], q7 = tp[i7];
#define CBF(Q,W) do { \
            ax = fmaf(W, __uint_as_float((Q).x << 16),        ax); \
            ay = fmaf(W, __uint_as_float((Q).x & 0xffff0000u), ay); \
            az = fmaf(W, __uint_as_float((Q).y << 16),        az); \
            aw = fmaf(W, __uint_as_float((Q).y & 0xffff0000u), aw); } while (0)
        CBF(q0,w0); CBF(q1,w1); CBF(q2,w2); CBF(q3,w3);
        CBF(q4,w4); CBF(q5,w5); CBF(q6,w6); CBF(q7,w7);
#undef CBF
    } else {
        const float4* tp = (const float4*)table + (size_t)l * TBL;
        const float4 f0 = tp[i0], f1 = tp[i1], f2 = tp[i2], f3 = tp[i3];
        const float4 f4 = tp[i4], f5 = tp[i5], f6 = tp[i6], f7 = tp[i7];
#define CF(F,W) do { \
            ax = fmaf(W, (F).x, ax); ay = fmaf(W, (F).y, ay); \
            az = fmaf(W, (F).z, az); aw = fmaf(W, (F).w, aw); } while (0)
        CF(f0,w0); CF(f1,w1); CF(f2,w2); CF(f3,w3);
        CF(f4,w4); CF(f5,w5); CF(f6,w6); CF(f7,w7);
#undef CF
    }
    // reduce over the 4 k-lanes
    ax += __shfl_xor(ax, 1, 64); ay += __shfl_xor(ay, 1, 64);
    az += __shfl_xor(az, 1, 64); aw += __shfl_xor(aw, 1, 64);
    ax += __shfl_xor(ax, 2, 64); ay += __shfl_xor(ay, 2, 64);
    az += __shfl_xor(az, 2, 64); aw += __shfl_xor(aw, 2, 64);

    // mean(K) * window; lane k stores component k of this level
    const float den = fmaxf(8.f * (float)l * crv, 1e-12f);
    const float s = 0.25f * erff(rsqrtf(den));
    const float v = (k & 1) ? ((k & 2) ? aw : ay) : ((k & 2) ? az : ax);
    const int f = k * LVL + l;
    const int a = ((f >> 5) << 9) + (((f >> 3) & 3) << 7) + (c << 3) + (f & 7);
    hswz[(size_t)tile * 1024 + a] = f2bf(v * s);
}

// ---------- kernel 2: MFMA MLP, wave = 16-point tile ----------
__global__ __launch_bounds__(256, 4) void ingp_mlp(
    const unsigned short* __restrict__ hswz,
    const unsigned short* __restrict__ frag,
    float* __restrict__ out, int npts)
{
    __shared__ __align__(16) char lds[4][2][2304];
    const int t    = threadIdx.x;
    const int lane = t & 63;
    const int wv   = t >> 6;
    const int c    = lane & 15;
    const int g    = lane >> 4;
    const int tile = blockIdx.x * 4 + wv;
    char* bufA = lds[wv][0];
    char* bufB = lds[wv][1];

    const short8* Fa = (const short8*)frag;
    const f32x4*  Fb = (const f32x4*)(frag + 10240);
    const short8 zf = {0,0,0,0,0,0,0,0};

    // ---- GEMM1: h1 = selu(W1 @ h + b1), K=64; features 40..63 are zero:
    // hb1 (ks=1 slice) is nonzero only for g==0 (features 32..39), matching a1.
    const short8* Hf = (const short8*)(hswz + (size_t)tile * 1024);
    const short8 hb0 = Hf[lane];
    short8 hb1 = zf;
    if (g == 0) hb1 = Hf[64 + lane];
    f32x4 acc[4];
#pragma unroll
    for (int mt = 0; mt < 4; ++mt) {
        const short8 a0 = Fa[(mt*2    )*64 + lane];
        const short8 a1 = Fa[(mt*2 + 1)*64 + lane];
        f32x4 acr = {0.f, 0.f, 0.f, 0.f};
        acr = __builtin_amdgcn_mfma_f32_16x16x32_bf16(a0, hb0, acr, 0, 0, 0);
        acr = __builtin_amdgcn_mfma_f32_16x16x32_bf16(a1, hb1, acr, 0, 0, 0);
        acc[mt] = acr;
    }
#pragma unroll
    for (int mt = 0; mt < 4; ++mt) {
        const f32x4 bb = Fb[mt*64 + lane];
        unsigned short h4[4];
#pragma unroll
        for (int r = 0; r < 4; ++r) h4[r] = f2bf(selu_f(acc[mt][r] + bb[r]));
        uint2 pk;
        pk.x = (unsigned)h4[0] | ((unsigned)h4[1] << 16);
        pk.y = (unsigned)h4[2] | ((unsigned)h4[3] << 16);
        *(uint2*)(bufA + c * 144 + mt * 32 + g * 8) = pk;
    }
    __syncthreads();

    // ---- GEMM2: h2 = selu(W2 @ h1 + b2), K=64 -> 2 k-slices ----
    short8 h1f[2];
#pragma unroll
    for (int ks = 0; ks < 2; ++ks)
        h1f[ks] = *(const short8*)(bufA + c * 144 + ks * 64 + g * 16);
    f32x4 acc2[4];
#pragma unroll
    for (int mt = 0; mt < 4; ++mt) {
        f32x4 acr = {0.f, 0.f, 0.f, 0.f};
#pragma unroll
        for (int ks = 0; ks < 2; ++ks) {
            const short8 af = Fa[(8 + mt*2 + ks)*64 + lane];
            acr = __builtin_amdgcn_mfma_f32_16x16x32_bf16(af, h1f[ks], acr, 0, 0, 0);
        }
        acc2[mt] = acr;
    }
    __syncthreads();
#pragma unroll
    for (int mt = 0; mt < 4; ++mt) {
        const f32x4 bb = Fb[(4 + mt)*64 + lane];
        unsigned short h4[4];
#pragma unroll
        for (int r = 0; r < 4; ++r) h4[r] = f2bf(selu_f(acc2[mt][r] + bb[r]));
        uint2 pk;
        pk.x = (unsigned)h4[0] | ((unsigned)h4[1] << 16);
        pk.y = (unsigned)h4[2] | ((unsigned)h4[3] << 16);
        *(uint2*)(bufB + c * 144 + mt * 32 + g * 8) = pk;
    }
    __syncthreads();

    // ---- GEMM3: o = W3 @ h2 + b3 (29 rows padded to 32), K=64 -> 2 slices ----
    short8 h2f[2];
#pragma unroll
    for (int ks = 0; ks < 2; ++ks)
        h2f[ks] = *(const short8*)(bufB + c * 144 + ks * 64 + g * 16);
    f32x4 o0 = {0.f,0.f,0.f,0.f}, o1 = {0.f,0.f,0.f,0.f};
#pragma unroll
    for (int ks = 0; ks < 2; ++ks) {
        const short8 af0 = Fa[(16 + ks)*64 + lane];
        o0 = __builtin_amdgcn_mfma_f32_16x16x32_bf16(af0, h2f[ks], o0, 0, 0, 0);
        const short8 af1 = Fa[(18 + ks)*64 + lane];
        o1 = __builtin_amdgcn_mfma_f32_16x16x32_bf16(af1, h2f[ks], o1, 0, 0, 0);
    }
    __syncthreads();   // bufA free again
    {
        const f32x4 bb0 = Fb[8*64 + lane];
        const f32x4 bb1 = Fb[9*64 + lane];
        f32x4 v0, v1;
#pragma unroll
        for (int r = 0; r < 4; ++r) { v0[r] = o0[r] + bb0[r]; v1[r] = o1[r] + bb1[r]; }
        *(f32x4*)(bufA + c * 144 + g * 16)      = v0;
        *(f32x4*)(bufA + c * 144 + 64 + g * 16) = v1;
    }
    __syncthreads();

    // ---- epilogue: quad per point ----
    {
        const int c2 = lane >> 2, part = lane & 3;
        const float* op = (const float*)(bufA + c2 * 144);
        const size_t p = (size_t)tile * 16 + c2;
        if ((int)p < npts) {
            float* dns  = out;
            float* rgbp = out + (size_t)npts;
            float* grdp = out + (size_t)npts * 4;
            float* shp  = out + (size_t)npts * 13;
            if (part == 0) {
                dns[p] = expf(op[0] - 4.f);
                rgbp[p*3+0] = op[1] + 0.5f;
                rgbp[p*3+1] = op[2] + 0.5f;
                rgbp[p*3+2] = op[3] + 0.5f;
            } else {
                const int r = part - 1;
                const float rr = op[1 + r] + 0.5f;
                grdp[p*9 + r*3 + 0] = rr * tanhf(op[4 + r*3 + 0]);
                grdp[p*9 + r*3 + 1] = rr * tanhf(op[4 + r*3 + 1]);
                grdp[p*9 + r*3 + 2] = rr * tanhf(op[4 + r*3 + 2]);
            }
#pragma unroll
            for (int s = 0; s < 4; ++s)
                shp[p*16 + part*4 + s] = op[13 + part*4 + s];
        }
    }
}

extern "C" void kernel_launch(void* const* d_in, const int* in_sizes, int n_in,
                              void* d_out, int out_size, void* d_ws, size_t ws_size,
                              hipStream_t stream) {
    const float* x     = (const float*)d_in[0];
    const float* cr    = (const float*)d_in[1];
    const float* eps   = (const float*)d_in[2];
    const float* table = (const float*)d_in[3];
    const float* W1    = (const float*)d_in[4];
    const float* b1    = (const float*)d_in[5];
    const float* W2    = (const float*)d_in[6];
    const float* b2    = (const float*)d_in[7];
    const float* W3    = (const float*)d_in[8];
    const float* b3    = (const float*)d_in[9];
    float* out = (float*)d_out;

    const int npts   = in_sizes[0] / 3;
    const int nunits = npts * LVL;
    const size_t ntiles = (size_t)(npts + 15) / 16;
    const size_t tblbf_bytes = (size_t)TBL * LVL * 8;     // 5,242,880
    const size_t frag_bytes  = 30720;
    const size_t hswz_bytes  = ntiles * 2048;
    const bool   bfpath = ws_size >= tblbf_bytes + frag_bytes + hswz_bytes;

    char* wsb = (char*)d_ws;
    uint2*          tblbf;
    unsigned short* frag;
    unsigned short* hswz;
    if (bfpath) {
        tblbf = (uint2*)wsb;
        frag  = (unsigned short*)(wsb + tblbf_bytes);
        hswz  = (unsigned short*)(wsb + tblbf_bytes + frag_bytes);
    } else {
        tblbf = (uint2*)table;   // unused in fp32 path
        frag  = (unsigned short*)wsb;
        hswz  = (unsigned short*)(wsb + frag_bytes);
    }

    ResArr res;
    const double bg = exp(log(pow(2.0, 10.0)) / 9.0);
    for (int l = 0; l < LVL; ++l) res.r[l] = (float)floor(16.0 * pow(bg, (double)l));

    if (bfpath)
        hipLaunchKernelGGL(cvt_table, dim3((TBL*LVL + 255)/256), dim3(256), 0, stream,
                           (const float4*)table, tblbf);
    hipLaunchKernelGGL(build_frags, dim3(8), dim3(256), 0, stream,
                       W1, b1, W2, b2, W3, b3, frag);

    const int grid1 = (nunits + 63) / 64;   // 64 units x 4 k-lanes per block
    if (bfpath)
        hipLaunchKernelGGL(ingp_gather<true>, dim3(grid1), dim3(256), 0, stream,
                           x, cr, eps, table, tblbf, hswz, nunits, npts, res);
    else
        hipLaunchKernelGGL(ingp_gather<false>, dim3(grid1), dim3(256), 0, stream,
                           x, cr, eps, table, tblbf, hswz, nunits, npts, res);

    const int grid2 = (npts + 63) / 64;
    hipLaunchKernelGGL(ingp_mlp, dim3(grid2), dim3(256), 0, stream,
                       hswz, frag, out, npts);
}

// Round 10
// 127.519 us; speedup vs baseline: 1.4657x; 1.2739x over previous
//
#include <hip/hip_runtime.h>
#include <hip/hip_bf16.h>
#include <math.h>

#define LVL 10
#define TBL 65536u
#define HIDN 64
#define OUTD 29
#define DIN 40

typedef __attribute__((ext_vector_type(8))) short short8;
typedef __attribute__((ext_vector_type(4))) float f32x4;

struct ResArr { float r[LVL]; };

// linear-table geometry (levels 0..3): S = res+1, B = entry base
#define S0 17
#define S1 21
#define S2 26
#define S3 33
#define B0 0
#define B1 4913          // 17^3
#define B2 14174         // +21^3
#define B3 31750         // +26^3
#define LIN_ENTRIES 67687 // +33^3

__device__ __forceinline__ unsigned short f2bf(float v) {
    __hip_bfloat16 b = __float2bfloat16(v);
    return __builtin_bit_cast(unsigned short, b);
}
__device__ __forceinline__ float selu_f(float v) {
    return v > 0.f ? 1.0507009873554805f * v
                   : 1.7580993408473766f * (__expf(v) - 1.f);
}

// ---------- kernel 0a: fp32 table -> bf16 hashed table, levels 4..9 ----------
__global__ __launch_bounds__(256) void cvt_table6(const float4* __restrict__ tbl,
                                                  uint2* __restrict__ tblbf) {
    const int i = blockIdx.x * 256 + threadIdx.x;
    if (i >= (int)(TBL * 6)) return;
    const float4 f = tbl[i + 4 * TBL];
    uint2 q;
    q.x = (unsigned)f2bf(f.x) | ((unsigned)f2bf(f.y) << 16);
    q.y = (unsigned)f2bf(f.z) | ((unsigned)f2bf(f.w) << 16);
    tblbf[i] = q;
}

// ---------- kernel 0c: linear z-pair tables for levels 0..3 ----------
// entry (x,y,z) = 16B: {bf16x4 tbl[hash(x,y,z)], bf16x4 tbl[hash(x,y,z+1)]}
__global__ __launch_bounds__(256) void build_lin(const float* __restrict__ table,
                                                 uint4* __restrict__ lin) {
    const int id = blockIdx.x * 256 + threadIdx.x;
    if (id >= LIN_ENTRIES) return;
    int l, S, B, rem;
    if (id < B1)      { l = 0; S = S0; B = B0; rem = id; }
    else if (id < B2) { l = 1; S = S1; B = B1; rem = id - B1; }
    else if (id < B3) { l = 2; S = S2; B = B2; rem = id - B2; }
    else              { l = 3; S = S3; B = B3; rem = id - B3; }
    const int z = rem % S, xy = rem / S, y = xy % S, x = xy / S;
    const int z1 = (z + 1 < S) ? z + 1 : z;
    const unsigned h0 = ((unsigned)x ^ (unsigned)y * 2654435761u ^ (unsigned)z  * 805459861u) & (TBL - 1u);
    const unsigned h1 = ((unsigned)x ^ (unsigned)y * 2654435761u ^ (unsigned)z1 * 805459861u) & (TBL - 1u);
    const float4* tl = (const float4*)table + (size_t)l * TBL;
    const float4 a = tl[h0], b = tl[h1];
    uint4 q;
    q.x = (unsigned)f2bf(a.x) | ((unsigned)f2bf(a.y) << 16);
    q.y = (unsigned)f2bf(a.z) | ((unsigned)f2bf(a.w) << 16);
    q.z = (unsigned)f2bf(b.x) | ((unsigned)f2bf(b.y) << 16);
    q.w = (unsigned)f2bf(b.z) | ((unsigned)f2bf(b.w) << 16);
    lin[B + (x * S + y) * S + z] = q;
}

// ---------- kernel 0b: weight/bias fragments (30720 B) ----------
__global__ __launch_bounds__(256) void build_frags(
    const float* __restrict__ W1, const float* __restrict__ b1,
    const float* __restrict__ W2, const float* __restrict__ b2,
    const float* __restrict__ W3, const float* __restrict__ b3,
    unsigned short* __restrict__ frag) {
    const int i = blockIdx.x * 256 + threadIdx.x;
    const int lane = i & 63, c = lane & 15, g = lane >> 4;
    if (i < 1280) {
        const int slot = i >> 6;
        float v[8];
#pragma unroll
        for (int j = 0; j < 8; ++j) v[j] = 0.f;
        if (slot < 8) {
            const int mt = slot >> 1, half = slot & 1, row = mt * 16 + c;
            if (half == 0) { for (int j = 0; j < 8; ++j) v[j] = W1[row*DIN + g*8 + j]; }
            else if (g == 0) { for (int j = 0; j < 8; ++j) v[j] = W1[row*DIN + 32 + j]; }
        } else if (slot < 16) {
            const int s = slot - 8, mt = s >> 1, ks = s & 1, row = mt * 16 + c;
            for (int j = 0; j < 8; ++j) v[j] = W2[row*HIDN + ks*32 + g*8 + j];
        } else {
            const int s = slot - 16, rt = s >> 1, ks = s & 1, row = rt * 16 + c;
            if (row < OUTD) { for (int j = 0; j < 8; ++j) v[j] = W3[row*HIDN + ks*32 + g*8 + j]; }
        }
        short8 r;
#pragma unroll
        for (int j = 0; j < 8; ++j) r[j] = (short)f2bf(v[j]);
        ((short8*)frag)[i] = r;
    } else if (i < 1920) {
        const int s = (i - 1280) >> 6;   // 0..9
        f32x4 v = {0.f, 0.f, 0.f, 0.f};
#pragma unroll
        for (int r = 0; r < 4; ++r) {
            if (s < 4)      v[r] = b1[s*16 + g*4 + r];
            else if (s < 8) v[r] = b2[(s-4)*16 + g*4 + r];
            else { const int row = (s-8)*16 + g*4 + r; v[r] = (row < OUTD) ? b3[row] : 0.f; }
        }
        ((f32x4*)(frag + 10240))[i - 1280] = v;
    }
}

// ---------- kernel 1: gather; blockIdx.y = LEVEL (wave-uniform) ----------
// lanes 4u..4u+3 hold k=0..3 for one point -> shfl_xor(1,2) k-reduce.
// l<4: 4x16B loads from linear z-pair table; l>=4: 8x8B hashed bf16.
template<bool BF>
__global__ __launch_bounds__(256, 6) void ingp_gather(
    const float* __restrict__ xg, const float* __restrict__ crg,
    const float* __restrict__ epsg, const float* __restrict__ table,
    const uint2* __restrict__ tblbf, const uint4* __restrict__ lintab,
    unsigned short* __restrict__ hswz, int npts, ResArr res)
{
    const int t  = threadIdx.x;
    const int k  = t & 3;
    const int pg = blockIdx.x * 64 + (t >> 2);
    const int l  = blockIdx.y;
    if (pg >= npts) return;
    const int tile = pg >> 4, c = pg & 15;

    float rs = res.r[0];
    rs = (l == 1) ? res.r[1] : rs;  rs = (l == 2) ? res.r[2] : rs;
    rs = (l == 3) ? res.r[3] : rs;  rs = (l == 4) ? res.r[4] : rs;
    rs = (l == 5) ? res.r[5] : rs;  rs = (l == 6) ? res.r[6] : rs;
    rs = (l == 7) ? res.r[7] : rs;  rs = (l == 8) ? res.r[8] : rs;
    rs = (l == 9) ? res.r[9] : rs;

    const float crv = crg[pg];
    const float tc  = 0.3f * crv;
    const float cvx = fmaf(4.f, xg[pg*3+0], -2.f);
    const float cvy = fmaf(4.f, xg[pg*3+1], -2.f);
    const float cvz = fmaf(4.f, xg[pg*3+2], -2.f);
    const float* ep = epsg + ((size_t)pg * 4 + k) * 3;
    const float sx = fmaf(fminf(fmaxf(fmaf(ep[0], tc, cvx), -1.f), 1.f), 0.25f, 0.5f);
    const float sy = fmaf(fminf(fmaxf(fmaf(ep[1], tc, cvy), -1.f), 1.f), 0.25f, 0.5f);
    const float sz = fmaf(fminf(fmaxf(fmaf(ep[2], tc, cvz), -1.f), 1.f), 0.25f, 0.5f);

    const float xs = sx * rs, ys = sy * rs, zs = sz * rs;
    const float fx = floorf(xs), fy = floorf(ys), fz = floorf(zs);
    const float frx = xs - fx, fry = ys - fy, frz = zs - fz;
    const int   cx = (int)fx, cy = (int)fy, cz = (int)fz;
    const float wx1 = frx, wx0 = 1.f - frx;
    const float wy1 = fry, wy0 = 1.f - fry;
    const float wz1 = frz, wz0 = 1.f - frz;
    const float w0 = wx0*wy0*wz0, w1 = wx0*wy0*wz1, w2 = wx0*wy1*wz0, w3 = wx0*wy1*wz1;
    const float w4 = wx1*wy0*wz0, w5 = wx1*wy0*wz1, w6 = wx1*wy1*wz0, w7 = wx1*wy1*wz1;

    float ax = 0.f, ay = 0.f, az = 0.f, aw = 0.f;
    if (BF && l < 4) {
        const int S = (l == 0) ? S0 : (l == 1) ? S1 : (l == 2) ? S2 : S3;
        const int B = (l == 0) ? B0 : (l == 1) ? B1 : (l == 2) ? B2 : B3;
        const uint4* lp = lintab + B;
        const int i00 = (cx * S + cy) * S + cz;   // (x0,y0)
        const int i01 = i00 + S;                  // (x0,y1)
        const int i10 = i00 + S * S;              // (x1,y0)
        const int i11 = i10 + S;                  // (x1,y1)
        const uint4 q00 = lp[i00], q01 = lp[i01], q10 = lp[i10], q11 = lp[i11];
#define CPAIR(Q,WA,WB) do { \
            ax = fmaf(WA, __uint_as_float((Q).x << 16),        ax); \
            ax = fmaf(WB, __uint_as_float((Q).z << 16),        ax); \
            ay = fmaf(WA, __uint_as_float((Q).x & 0xffff0000u), ay); \
            ay = fmaf(WB, __uint_as_float((Q).z & 0xffff0000u), ay); \
            az = fmaf(WA, __uint_as_float((Q).y << 16),        az); \
            az = fmaf(WB, __uint_as_float((Q).w << 16),        az); \
            aw = fmaf(WA, __uint_as_float((Q).y & 0xffff0000u), aw); \
            aw = fmaf(WB, __uint_as_float((Q).w & 0xffff0000u), aw); } while (0)
        CPAIR(q00, w0, w1); CPAIR(q01, w2, w3);
        CPAIR(q10, w4, w5); CPAIR(q11, w6, w7);
#undef CPAIR
    } else {
        const unsigned ux = (unsigned)cx, uy = (unsigned)cy, uz = (unsigned)cz;
        const unsigned hx0 = ux,               hx1 = ux + 1u;
        const unsigned hy0 = uy * 2654435761u, hy1 = hy0 + 2654435761u;
        const unsigned hz0 = uz * 805459861u,  hz1 = hz0 + 805459861u;
        const unsigned i0 = (hx0^hy0^hz0) & (TBL-1u);
        const unsigned i1 = (hx0^hy0^hz1) & (TBL-1u);
        const unsigned i2 = (hx0^hy1^hz0) & (TBL-1u);
        const unsigned i3 = (hx0^hy1^hz1) & (TBL-1u);
        const unsigned i4 = (hx1^hy0^hz0) & (TBL-1u);
        const unsigned i5 = (hx1^hy0^hz1) & (TBL-1u);
        const unsigned i6 = (hx1^hy1^hz0) & (TBL-1u);
        const unsigned i7 = (hx1^hy1^hz1) & (TBL-1u);
        if (BF) {
            const uint2* tp = tblbf + (size_t)(l - 4) * TBL;
            const uint2 q0 = tp[i0], q1 = tp[i1], q2 = tp[i2], q3 = tp[i3];
            const uint2 q4 = tp[i4], q5 = tp[i5], q6 = tp[i6], q7 = tp[i7];
#define CBF(Q,W) do { \
                ax = fmaf(W, __uint_as_float((Q).x << 16),        ax); \
                ay = fmaf(W, __uint_as_float((Q).x & 0xffff0000u), ay); \
                az = fmaf(W, __uint_as_float((Q).y << 16),        az); \
                aw = fmaf(W, __uint_as_float((Q).y & 0xffff0000u), aw); } while (0)
            CBF(q0,w0); CBF(q1,w1); CBF(q2,w2); CBF(q3,w3);
            CBF(q4,w4); CBF(q5,w5); CBF(q6,w6); CBF(q7,w7);
#undef CBF
        } else {
            const float4* tp = (const float4*)table + (size_t)l * TBL;
            const float4 f0 = tp[i0], f1 = tp[i1], f2 = tp[i2], f3 = tp[i3];
            const float4 f4 = tp[i4], f5 = tp[i5], f6 = tp[i6], f7 = tp[i7];
#define CF(F,W) do { \
                ax = fmaf(W, (F).x, ax); ay = fmaf(W, (F).y, ay); \
                az = fmaf(W, (F).z, az); aw = fmaf(W, (F).w, aw); } while (0)
            CF(f0,w0); CF(f1,w1); CF(f2,w2); CF(f3,w3);
            CF(f4,w4); CF(f5,w5); CF(f6,w6); CF(f7,w7);
#undef CF
        }
    }
    // reduce over the 4 k-lanes
    ax += __shfl_xor(ax, 1, 64); ay += __shfl_xor(ay, 1, 64);
    az += __shfl_xor(az, 1, 64); aw += __shfl_xor(aw, 1, 64);
    ax += __shfl_xor(ax, 2, 64); ay += __shfl_xor(ay, 2, 64);
    az += __shfl_xor(az, 2, 64); aw += __shfl_xor(aw, 2, 64);

    // mean(K) * window; lane k stores component k of this level
    const float den = fmaxf(8.f * (float)l * crv, 1e-12f);
    const float s = 0.25f * erff(rsqrtf(den));
    const float v = (k & 1) ? ((k & 2) ? aw : ay) : ((k & 2) ? az : ax);
    const int f = k * LVL + l;
    const int a = ((f >> 5) << 9) + (((f >> 3) & 3) << 7) + (c << 3) + (f & 7);
    hswz[(size_t)tile * 1024 + a] = f2bf(v * s);
}

// ---------- kernel 2: MFMA MLP, wave = 16-point tile ----------
__global__ __launch_bounds__(256, 4) void ingp_mlp(
    const unsigned short* __restrict__ hswz,
    const unsigned short* __restrict__ frag,
    float* __restrict__ out, int npts)
{
    __shared__ __align__(16) char lds[4][2][2304];
    const int t    = threadIdx.x;
    const int lane = t & 63;
    const int wv   = t >> 6;
    const int c    = lane & 15;
    const int g    = lane >> 4;
    const int tile = blockIdx.x * 4 + wv;
    char* bufA = lds[wv][0];
    char* bufB = lds[wv][1];

    const short8* Fa = (const short8*)frag;
    const f32x4*  Fb = (const f32x4*)(frag + 10240);
    const short8 zf = {0,0,0,0,0,0,0,0};

    const short8* Hf = (const short8*)(hswz + (size_t)tile * 1024);
    const short8 hb0 = Hf[lane];
    short8 hb1 = zf;
    if (g == 0) hb1 = Hf[64 + lane];
    f32x4 acc[4];
#pragma unroll
    for (int mt = 0; mt < 4; ++mt) {
        const short8 a0 = Fa[(mt*2    )*64 + lane];
        const short8 a1 = Fa[(mt*2 + 1)*64 + lane];
        f32x4 acr = {0.f, 0.f, 0.f, 0.f};
        acr = __builtin_amdgcn_mfma_f32_16x16x32_bf16(a0, hb0, acr, 0, 0, 0);
        acr = __builtin_amdgcn_mfma_f32_16x16x32_bf16(a1, hb1, acr, 0, 0, 0);
        acc[mt] = acr;
    }
#pragma unroll
    for (int mt = 0; mt < 4; ++mt) {
        const f32x4 bb = Fb[mt*64 + lane];
        unsigned short h4[4];
#pragma unroll
        for (int r = 0; r < 4; ++r) h4[r] = f2bf(selu_f(acc[mt][r] + bb[r]));
        uint2 pk;
        pk.x = (unsigned)h4[0] | ((unsigned)h4[1] << 16);
        pk.y = (unsigned)h4[2] | ((unsigned)h4[3] << 16);
        *(uint2*)(bufA + c * 144 + mt * 32 + g * 8) = pk;
    }
    __syncthreads();

    short8 h1f[2];
#pragma unroll
    for (int ks = 0; ks < 2; ++ks)
        h1f[ks] = *(const short8*)(bufA + c * 144 + ks * 64 + g * 16);
    f32x4 acc2[4];
#pragma unroll
    for (int mt = 0; mt < 4; ++mt) {
        f32x4 acr = {0.f, 0.f, 0.f, 0.f};
#pragma unroll
        for (int ks = 0; ks < 2; ++ks) {
            const short8 af = Fa[(8 + mt*2 + ks)*64 + lane];
            acr = __builtin_amdgcn_mfma_f32_16x16x32_bf16(af, h1f[ks], acr, 0, 0, 0);
        }
        acc2[mt] = acr;
    }
    __syncthreads();
#pragma unroll
    for (int mt = 0; mt < 4; ++mt) {
        const f32x4 bb = Fb[(4 + mt)*64 + lane];
        unsigned short h4[4];
#pragma unroll
        for (int r = 0; r < 4; ++r) h4[r] = f2bf(selu_f(acc2[mt][r] + bb[r]));
        uint2 pk;
        pk.x = (unsigned)h4[0] | ((unsigned)h4[1] << 16);
        pk.y = (unsigned)h4[2] | ((unsigned)h4[3] << 16);
        *(uint2*)(bufB + c * 144 + mt * 32 + g * 8) = pk;
    }
    __syncthreads();

    short8 h2f[2];
#pragma unroll
    for (int ks = 0; ks < 2; ++ks)
        h2f[ks] = *(const short8*)(bufB + c * 144 + ks * 64 + g * 16);
    f32x4 o0 = {0.f,0.f,0.f,0.f}, o1 = {0.f,0.f,0.f,0.f};
#pragma unroll
    for (int ks = 0; ks < 2; ++ks) {
        const short8 af0 = Fa[(16 + ks)*64 + lane];
        o0 = __builtin_amdgcn_mfma_f32_16x16x32_bf16(af0, h2f[ks], o0, 0, 0, 0);
        const short8 af1 = Fa[(18 + ks)*64 + lane];
        o1 = __builtin_amdgcn_mfma_f32_16x16x32_bf16(af1, h2f[ks], o1, 0, 0, 0);
    }
    __syncthreads();
    {
        const f32x4 bb0 = Fb[8*64 + lane];
        const f32x4 bb1 = Fb[9*64 + lane];
        f32x4 v0, v1;
#pragma unroll
        for (int r = 0; r < 4; ++r) { v0[r] = o0[r] + bb0[r]; v1[r] = o1[r] + bb1[r]; }
        *(f32x4*)(bufA + c * 144 + g * 16)      = v0;
        *(f32x4*)(bufA + c * 144 + 64 + g * 16) = v1;
    }
    __syncthreads();

    {
        const int c2 = lane >> 2, part = lane & 3;
        const float* op = (const float*)(bufA + c2 * 144);
        const size_t p = (size_t)tile * 16 + c2;
        if ((int)p < npts) {
            float* dns  = out;
            float* rgbp = out + (size_t)npts;
            float* grdp = out + (size_t)npts * 4;
            float* shp  = out + (size_t)npts * 13;
            if (part == 0) {
                dns[p] = expf(op[0] - 4.f);
                rgbp[p*3+0] = op[1] + 0.5f;
                rgbp[p*3+1] = op[2] + 0.5f;
                rgbp[p*3+2] = op[3] + 0.5f;
            } else {
                const int r = part - 1;
                const float rr = op[1 + r] + 0.5f;
                grdp[p*9 + r*3 + 0] = rr * tanhf(op[4 + r*3 + 0]);
                grdp[p*9 + r*3 + 1] = rr * tanhf(op[4 + r*3 + 1]);
                grdp[p*9 + r*3 + 2] = rr * tanhf(op[4 + r*3 + 2]);
            }
#pragma unroll
            for (int s = 0; s < 4; ++s)
                shp[p*16 + part*4 + s] = op[13 + part*4 + s];
        }
    }
}

extern "C" void kernel_launch(void* const* d_in, const int* in_sizes, int n_in,
                              void* d_out, int out_size, void* d_ws, size_t ws_size,
                              hipStream_t stream) {
    const float* x     = (const float*)d_in[0];
    const float* cr    = (const float*)d_in[1];
    const float* eps   = (const float*)d_in[2];
    const float* table = (const float*)d_in[3];
    const float* W1    = (const float*)d_in[4];
    const float* b1    = (const float*)d_in[5];
    const float* W2    = (const float*)d_in[6];
    const float* b2    = (const float*)d_in[7];
    const float* W3    = (const float*)d_in[8];
    const float* b3    = (const float*)d_in[9];
    float* out = (float*)d_out;

    const int npts   = in_sizes[0] / 3;
    const size_t ntiles = (size_t)(npts + 15) / 16;
    const size_t tblbf_bytes = (size_t)TBL * 6 * 8;       // 3,145,728 (levels 4..9)
    const size_t lin_bytes   = (size_t)LIN_ENTRIES * 16;  // 1,082,992
    const size_t frag_bytes  = 30720;
    const size_t hswz_bytes  = ntiles * 2048;
    const bool   bfpath = ws_size >= tblbf_bytes + lin_bytes + frag_bytes + hswz_bytes;

    char* wsb = (char*)d_ws;
    uint2*          tblbf;
    uint4*          lintab;
    unsigned short* frag;
    unsigned short* hswz;
    if (bfpath) {
        tblbf  = (uint2*)wsb;
        lintab = (uint4*)(wsb + tblbf_bytes);
        frag   = (unsigned short*)(wsb + tblbf_bytes + lin_bytes);
        hswz   = (unsigned short*)(wsb + tblbf_bytes + lin_bytes + frag_bytes);
    } else {
        tblbf  = (uint2*)table;   // unused in fp32 path
        lintab = (uint4*)table;
        frag   = (unsigned short*)wsb;
        hswz   = (unsigned short*)(wsb + frag_bytes);
    }

    ResArr res;
    const double bg = exp(log(pow(2.0, 10.0)) / 9.0);
    for (int l = 0; l < LVL; ++l) res.r[l] = (float)floor(16.0 * pow(bg, (double)l));

    if (bfpath) {
        hipLaunchKernelGGL(cvt_table6, dim3((TBL*6 + 255)/256), dim3(256), 0, stream,
                           (const float4*)table, tblbf);
        hipLaunchKernelGGL(build_lin, dim3((LIN_ENTRIES + 255)/256), dim3(256), 0, stream,
                           table, lintab);
    }
    hipLaunchKernelGGL(build_frags, dim3(8), dim3(256), 0, stream,
                       W1, b1, W2, b2, W3, b3, frag);

    const int gx = (npts + 63) / 64;
    if (bfpath)
        hipLaunchKernelGGL(ingp_gather<true>, dim3(gx, LVL), dim3(256), 0, stream,
                           x, cr, eps, table, tblbf, lintab, hswz, npts, res);
    else
        hipLaunchKernelGGL(ingp_gather<false>, dim3(gx, LVL), dim3(256), 0, stream,
                           x, cr, eps, table, tblbf, lintab, hswz, npts, res);

    const int grid2 = (npts + 63) / 64;
    hipLaunchKernelGGL(ingp_mlp, dim3(grid2), dim3(256), 0, stream,
                       hswz, frag, out, npts);
}